// Round 2
// baseline (1265.726 us; speedup 1.0000x reference)
//
#include <hip/hip_runtime.h>

// ---------- types ----------
typedef __attribute__((ext_vector_type(8))) short short8;   // 8 x bf16
typedef __attribute__((ext_vector_type(4))) float f32x4;

typedef __attribute__((address_space(1))) const void gas1_t;
typedef __attribute__((address_space(3))) void las3_t;
#define GLL16(g, l) __builtin_amdgcn_global_load_lds((gas1_t*)(g), (las3_t*)(l), 16, 0, 0)

__device__ inline unsigned short f2bf(float f) {
  union { float f; unsigned int u; } v; v.f = f;
  unsigned int r = v.u + 0x7FFFu + ((v.u >> 16) & 1u);
  return (unsigned short)(r >> 16);
}

// ---------- LayerNorm (f32 in, bf16 out), one row per block ----------
__global__ __launch_bounds__(256) void ln_kernel(const float* __restrict__ x,
                                                 const float* __restrict__ w,
                                                 const float* __restrict__ bia,
                                                 unsigned short* __restrict__ out) {
  const int row = blockIdx.x;
  const int tid = threadIdx.x;
  const float* xr = x + (size_t)row * 2048;
  float4 a = *(const float4*)(xr + tid * 8);
  float4 b = *(const float4*)(xr + tid * 8 + 4);
  float s  = a.x + a.y + a.z + a.w + b.x + b.y + b.z + b.w;
  float s2 = a.x*a.x + a.y*a.y + a.z*a.z + a.w*a.w + b.x*b.x + b.y*b.y + b.z*b.z + b.w*b.w;
  #pragma unroll
  for (int off = 1; off < 64; off <<= 1) {
    s  += __shfl_xor(s, off);
    s2 += __shfl_xor(s2, off);
  }
  __shared__ float red[8];
  if ((tid & 63) == 0) { red[tid >> 6] = s; red[4 + (tid >> 6)] = s2; }
  __syncthreads();
  s  = red[0] + red[1] + red[2] + red[3];
  s2 = red[4] + red[5] + red[6] + red[7];
  const float mean = s * (1.f / 2048.f);
  const float var  = s2 * (1.f / 2048.f) - mean * mean;
  const float rstd = rsqrtf(var + 1e-5f);
  float4 wa = *(const float4*)(w + tid * 8), wb = *(const float4*)(w + tid * 8 + 4);
  float4 ba = *(const float4*)(bia + tid * 8), bb = *(const float4*)(bia + tid * 8 + 4);
  short8 o;
  o[0] = (short)f2bf((a.x - mean) * rstd * wa.x + ba.x);
  o[1] = (short)f2bf((a.y - mean) * rstd * wa.y + ba.y);
  o[2] = (short)f2bf((a.z - mean) * rstd * wa.z + ba.z);
  o[3] = (short)f2bf((a.w - mean) * rstd * wa.w + ba.w);
  o[4] = (short)f2bf((b.x - mean) * rstd * wb.x + bb.x);
  o[5] = (short)f2bf((b.y - mean) * rstd * wb.y + bb.y);
  o[6] = (short)f2bf((b.z - mean) * rstd * wb.z + bb.z);
  o[7] = (short)f2bf((b.w - mean) * rstd * wb.w + bb.w);
  *(short8*)(out + (size_t)row * 2048 + tid * 8) = o;
}

// ---------- f32 -> bf16 convert ----------
__global__ __launch_bounds__(256) void conv_kernel(const float* __restrict__ in,
                                                   unsigned short* __restrict__ out, int n) {
  size_t idx = ((size_t)blockIdx.x * 256 + threadIdx.x) * 8;
  if (idx >= (size_t)n) return;
  float4 a = *(const float4*)(in + idx);
  float4 b = *(const float4*)(in + idx + 4);
  short8 o;
  o[0] = (short)f2bf(a.x); o[1] = (short)f2bf(a.y);
  o[2] = (short)f2bf(a.z); o[3] = (short)f2bf(a.w);
  o[4] = (short)f2bf(b.x); o[5] = (short)f2bf(b.y);
  o[6] = (short)f2bf(b.z); o[7] = (short)f2bf(b.w);
  *(short8*)(out + idx) = o;
}

// ---------- GEMM: C[M,N] = A[M,K] * Bw[N,K]^T + bias; MODE epilogues ----------
// MODE 0: store bf16; MODE 1: relu + bf16; MODE 2: f32 out = res + acc + bias
template <int MODE>
__global__ __launch_bounds__(256) void gemm_bt(const unsigned short* __restrict__ A,
                                               const unsigned short* __restrict__ Bw,
                                               const float* __restrict__ bias,
                                               const float* __restrict__ res,
                                               void* __restrict__ outp,
                                               int M, int N, int K) {
  __shared__ unsigned short As[128 * 64];
  __shared__ unsigned short Bs[128 * 64];
  const int tid = threadIdx.x;
  const int l = tid & 63, wv = tid >> 6;
  const int l15 = l & 15, l4 = l >> 4;
  const int wr = wv >> 1, wc = wv & 1;
  const int m0 = blockIdx.y * 128, n0 = blockIdx.x * 128;

  f32x4 acc[4][4] = {};
  for (int k0 = 0; k0 < K; k0 += 64) {
    __syncthreads();
    #pragma unroll
    for (int i = 0; i < 4; ++i) {
      int e = i * 2048 + tid * 8;
      int r = e >> 6;
      int c = (e ^ ((r & 7) << 3)) & 63;  // pre-swizzled source, linear LDS dest
      GLL16(A + (size_t)(m0 + r) * K + k0 + c, As + e);
      GLL16(Bw + (size_t)(n0 + r) * K + k0 + c, Bs + e);
    }
    __syncthreads();
    #pragma unroll
    for (int kk = 0; kk < 64; kk += 32) {
      short8 af[4], bfr[4];
      #pragma unroll
      for (int m = 0; m < 4; ++m) {
        int r = wr * 64 + m * 16 + l15;
        int byt = (r * 128 + (kk + l4 * 8) * 2) ^ ((r & 7) << 4);
        af[m] = *(const short8*)((const char*)As + byt);
      }
      #pragma unroll
      for (int n = 0; n < 4; ++n) {
        int r = wc * 64 + n * 16 + l15;
        int byt = (r * 128 + (kk + l4 * 8) * 2) ^ ((r & 7) << 4);
        bfr[n] = *(const short8*)((const char*)Bs + byt);
      }
      #pragma unroll
      for (int m = 0; m < 4; ++m)
        #pragma unroll
        for (int n = 0; n < 4; ++n)
          acc[m][n] = __builtin_amdgcn_mfma_f32_16x16x32_bf16(af[m], bfr[n], acc[m][n], 0, 0, 0);
    }
  }
  #pragma unroll
  for (int m = 0; m < 4; ++m) {
    #pragma unroll
    for (int n = 0; n < 4; ++n) {
      #pragma unroll
      for (int r = 0; r < 4; ++r) {
        int row = m0 + wr * 64 + m * 16 + l4 * 4 + r;
        int col = n0 + wc * 64 + n * 16 + l15;
        float v = acc[m][n][r] + bias[col];
        if (MODE == 0) {
          ((unsigned short*)outp)[(size_t)row * N + col] = f2bf(v);
        } else if (MODE == 1) {
          ((unsigned short*)outp)[(size_t)row * N + col] = f2bf(v > 0.f ? v : 0.f);
        } else {
          ((float*)outp)[(size_t)row * N + col] = res[(size_t)row * N + col] + v;
        }
      }
    }
  }
}

// ---------- Flash attention: qkv bf16 [B*S, 6144] -> ctx bf16 [B*S, 2048] ----------
__global__ __launch_bounds__(256) void attn_kernel(const unsigned short* __restrict__ qkv,
                                                   const int* __restrict__ amask,
                                                   unsigned short* __restrict__ ctx) {
  __shared__ unsigned short Ks[32 * 128];   // XOR-swizzled rows
  __shared__ unsigned short Vt[128 * 56];   // V transposed [d][key], padded stride 56
  __shared__ unsigned short Pl[4][16 * 56]; // per-wave P buffer
  __shared__ int smask[32];

  const int qt = blockIdx.x, bh = blockIdx.y;
  const int b = bh >> 4, h = bh & 15;
  const int tid = threadIdx.x;
  const int wv = tid >> 6, l = tid & 63;
  const int l15 = l & 15, l4 = l >> 4;
  const int q0 = qt * 64 + wv * 16;
  const float scale = 0.08838834764831845f; // 1/sqrt(128)

  // Q fragments in registers (16 q-rows per wave)
  short8 qf[4];
  {
    const unsigned short* qp = qkv + (size_t)(b * 2048 + q0 + l15) * 6144 + h * 128;
    #pragma unroll
    for (int dc = 0; dc < 4; ++dc) qf[dc] = *(const short8*)(qp + dc * 32 + l4 * 8);
  }

  f32x4 o[8] = {};
  float mrun[4] = {-1e30f, -1e30f, -1e30f, -1e30f};
  float lsum[4] = {0.f, 0.f, 0.f, 0.f};

  for (int kt = 0; kt < 2048; kt += 32) {
    __syncthreads();
    // stage K (swizzled) and V (transposed)
    #pragma unroll
    for (int i = 0; i < 2; ++i) {
      int e = i * 2048 + tid * 8;
      int key = e >> 7, d = e & 127;
      const unsigned short* kp = qkv + (size_t)(b * 2048 + kt + key) * 6144 + 2048 + h * 128 + d;
      short8 kv = *(const short8*)kp;
      *(short8*)((char*)Ks + ((key * 256 + d * 2) ^ ((key & 7) << 4))) = kv;
      short8 vv = *(const short8*)(kp + 2048);
      #pragma unroll
      for (int j = 0; j < 8; ++j) Vt[(d + j) * 56 + key] = (unsigned short)vv[j];
    }
    if (tid < 32) smask[tid] = amask[b * 2048 + kt + tid];
    __syncthreads();

    // S = Q K^T (16q x 32k per wave)
    f32x4 sacc[2] = {};
    #pragma unroll
    for (int dc = 0; dc < 4; ++dc) {
      #pragma unroll
      for (int ck = 0; ck < 2; ++ck) {
        int key = ck * 16 + l15;
        short8 kf = *(const short8*)((const char*)Ks +
                     ((key * 256 + dc * 64 + l4 * 16) ^ ((key & 7) << 4)));
        sacc[ck] = __builtin_amdgcn_mfma_f32_16x16x32_bf16(qf[dc], kf, sacc[ck], 0, 0, 0);
      }
    }

    // online softmax in C-layout (row q = l4*4+r, col key = l15)
    float s[2][4];
    bool pad[2];
    #pragma unroll
    for (int ck = 0; ck < 2; ++ck) {
      pad[ck] = (smask[ck * 16 + l15] == 0);
      int kg = kt + ck * 16 + l15;
      #pragma unroll
      for (int r = 0; r < 4; ++r) {
        int qg = q0 + l4 * 4 + r;
        float v = sacc[ck][r] * scale + ((kg > qg) ? 1.0f : 0.0f); // additive causal (+1.0!)
        s[ck][r] = pad[ck] ? -1e30f : v;
      }
    }
    float mr[4], sc[4], ps[4], p[2][4];
    #pragma unroll
    for (int r = 0; r < 4; ++r) mr[r] = fmaxf(s[0][r], s[1][r]);
    #pragma unroll
    for (int off = 1; off < 16; off <<= 1)
      #pragma unroll
      for (int r = 0; r < 4; ++r) mr[r] = fmaxf(mr[r], __shfl_xor(mr[r], off));
    #pragma unroll
    for (int r = 0; r < 4; ++r) {
      float mn = fmaxf(mrun[r], mr[r]);
      sc[r] = __expf(mrun[r] - mn);
      mrun[r] = mn;
      float p0 = pad[0] ? 0.f : __expf(s[0][r] - mn);
      float p1 = pad[1] ? 0.f : __expf(s[1][r] - mn);
      p[0][r] = p0; p[1][r] = p1;
      ps[r] = p0 + p1;
    }
    #pragma unroll
    for (int off = 1; off < 16; off <<= 1)
      #pragma unroll
      for (int r = 0; r < 4; ++r) ps[r] += __shfl_xor(ps[r], off);
    #pragma unroll
    for (int r = 0; r < 4; ++r) lsum[r] = lsum[r] * sc[r] + ps[r];
    #pragma unroll
    for (int dc = 0; dc < 8; ++dc) {
      #pragma unroll
      for (int r = 0; r < 4; ++r) o[dc][r] *= sc[r];
    }
    // P -> LDS (bf16), reload as A-fragment
    #pragma unroll
    for (int ck = 0; ck < 2; ++ck)
      #pragma unroll
      for (int r = 0; r < 4; ++r)
        Pl[wv][(l4 * 4 + r) * 56 + ck * 16 + l15] = f2bf(p[ck][r]);
    short8 pa = *(const short8*)&Pl[wv][l15 * 56 + l4 * 8];
    #pragma unroll
    for (int dc = 0; dc < 8; ++dc) {
      short8 vf = *(const short8*)&Vt[(dc * 16 + l15) * 56 + l4 * 8];
      o[dc] = __builtin_amdgcn_mfma_f32_16x16x32_bf16(pa, vf, o[dc], 0, 0, 0);
    }
  }

  float inv[4];
  #pragma unroll
  for (int r = 0; r < 4; ++r) inv[r] = 1.0f / lsum[r];
  #pragma unroll
  for (int dc = 0; dc < 8; ++dc) {
    #pragma unroll
    for (int r = 0; r < 4; ++r) {
      int q = q0 + l4 * 4 + r;
      ctx[(size_t)(b * 2048 + q) * 2048 + h * 128 + dc * 16 + l15] = f2bf(o[dc][r] * inv[r]);
    }
  }
}

// ---------- launch ----------
extern "C" void kernel_launch(void* const* d_in, const int* in_sizes, int n_in,
                              void* d_out, int out_size, void* d_ws, size_t ws_size,
                              hipStream_t stream) {
  (void)in_sizes; (void)n_in; (void)out_size; (void)ws_size;
  const float* x    = (const float*)d_in[0];
  const int*   am   = (const int*)d_in[1];
  const float* ln1w = (const float*)d_in[2];
  const float* ln1b = (const float*)d_in[3];
  const float* win  = (const float*)d_in[4];
  const float* bin  = (const float*)d_in[5];
  const float* wout = (const float*)d_in[6];
  const float* bout = (const float*)d_in[7];
  const float* ln2w = (const float*)d_in[8];
  const float* ln2b = (const float*)d_in[9];
  const float* w1   = (const float*)d_in[10];
  const float* b1   = (const float*)d_in[11];
  const float* w2   = (const float*)d_in[12];
  const float* b2   = (const float*)d_in[13];
  float* out = (float*)d_out;

  char* ws = (char*)d_ws;
  unsigned short* hbuf = (unsigned short*)ws;                         // 32 MB: h, then ctx
  unsigned short* wbuf = (unsigned short*)(ws + 33554432);            // 24 MB: bf16 weights
  unsigned short* qkvb = (unsigned short*)(ws + 58720256);            // 96 MB: qkv, later h2
  unsigned short* midb = (unsigned short*)(ws + 58720256 + 33554432); // 4 MB (inside qkv region)

  // 1) h = LN1(x) -> bf16
  ln_kernel<<<dim3(8192), dim3(256), 0, stream>>>(x, ln1w, ln1b, hbuf);
  // 2) in_proj_w -> bf16
  conv_kernel<<<dim3(6144), dim3(256), 0, stream>>>(win, wbuf, 12582912);
  // 3) qkv = h @ Win^T + b  [8192, 6144] bf16
  gemm_bt<0><<<dim3(48, 64), dim3(256), 0, stream>>>(hbuf, wbuf, bin, (const float*)nullptr,
                                                     (void*)qkvb, 8192, 6144, 2048);
  // 4) attention -> ctx (reuses hbuf)
  attn_kernel<<<dim3(32, 64), dim3(256), 0, stream>>>(qkvb, am, hbuf);
  // 5) out_proj_w -> bf16
  conv_kernel<<<dim3(2048), dim3(256), 0, stream>>>(wout, wbuf, 4194304);
  // 6) d_out = x + ctx @ Wout^T + b  (f32)
  gemm_bt<2><<<dim3(16, 64), dim3(256), 0, stream>>>(hbuf, wbuf, bout, x,
                                                     (void*)out, 8192, 2048, 2048);
  // 7) h2 = LN2(d_out) -> bf16 (reuses qkv region)
  ln_kernel<<<dim3(8192), dim3(256), 0, stream>>>(out, ln2w, ln2b, qkvb);
  // 8) mlp_w1 -> bf16
  conv_kernel<<<dim3(256), dim3(256), 0, stream>>>(w1, wbuf, 524288);
  // 9) mid = relu(h2 @ W1^T + b1)  [8192, 256] bf16
  gemm_bt<1><<<dim3(2, 64), dim3(256), 0, stream>>>(qkvb, wbuf, b1, (const float*)nullptr,
                                                    (void*)midb, 8192, 256, 2048);
  // 10) mlp_w2 -> bf16
  conv_kernel<<<dim3(256), dim3(256), 0, stream>>>(w2, wbuf, 524288);
  // 11) d_out = d_out + mid @ W2^T + b2  (f32, in-place per-element)
  gemm_bt<2><<<dim3(16, 64), dim3(256), 0, stream>>>(midb, wbuf, b2, out,
                                                     (void*)out, 8192, 2048, 256);
}